// Round 13
// baseline (237.031 us; speedup 1.0000x reference)
//
#include <hip/hip_runtime.h>
#include <hip/hip_bf16.h>
#include <math.h>

#define DIMSZ 1024
#define HEADS 16
#define DHEAD 64
#define NSEQ  2048
#define BATCH 2
#define ROWS  (BATCH*NSEQ)        // 4096
#define SCALE 0.125f
#define LOG2E 1.4426950408889634f

typedef __attribute__((ext_vector_type(8))) short short8;
typedef __attribute__((ext_vector_type(4))) float floatx4;
typedef __attribute__((ext_vector_type(16))) float floatx16;
typedef __attribute__((ext_vector_type(4))) unsigned uintx4;

#define MFMA16(a,b,c) __builtin_amdgcn_mfma_f32_16x16x32_bf16(a,b,c,0,0,0)
#define MFMA32(a,b,c) __builtin_amdgcn_mfma_f32_32x32x16_bf16(a,b,c,0,0,0)

__device__ __forceinline__ void gl2lds16(const void* g, void* l) {
    __builtin_amdgcn_global_load_lds(
        (const __attribute__((address_space(1))) unsigned int*)g,
        (__attribute__((address_space(3))) unsigned int*)l, 16, 0, 0);
}

// branch-free RNE f32->bf16 (finite values only)
__device__ __forceinline__ unsigned short bf16r(float a) {
    unsigned u = __float_as_uint(a);
    u += 0x7fff + ((u >> 16) & 1);
    return (unsigned short)(u >> 16);
}
__device__ __forceinline__ unsigned pack_bf16(float a, float b) {
    unsigned ua = __float_as_uint(a), ub = __float_as_uint(b);
    ua += 0x7fff + ((ua >> 16) & 1);
    ub += 0x7fff + ((ub >> 16) & 1);
    return (ua >> 16) | (ub & 0xffff0000u);
}
__device__ __forceinline__ float2 bf2f(unsigned u) {
    float2 r;
    r.x = __uint_as_float(u << 16);
    r.y = __uint_as_float(u & 0xffff0000u);
    return r;
}
// RNE f32 pair -> packed bf16 dword in ONE VALU op
__device__ __forceinline__ unsigned cvtpk(float lo, float hi) {
    unsigned r;
    asm("v_cvt_pk_bf16_f32 %0, %1, %2" : "=v"(r) : "v"(lo), "v"(hi));
    return r;
}
// swap upper 32 lanes of a with lower 32 lanes of b
__device__ __forceinline__ void pl32swap(unsigned &a, unsigned &b) {
#if __has_builtin(__builtin_amdgcn_permlane32_swap)
    auto r = __builtin_amdgcn_permlane32_swap(a, b, false, false);
    a = (unsigned)r[0]; b = (unsigned)r[1];
#else
    asm volatile("v_permlane32_swap_b32 %0, %1" : "+v"(a), "+v"(b));
#endif
}
__device__ __forceinline__ float fexp2(float x) {
#if __has_builtin(__builtin_amdgcn_exp2f)
    return __builtin_amdgcn_exp2f(x);
#else
    return exp2f(x);
#endif
}
__device__ __forceinline__ float fsin_rev(float x) {
#if __has_builtin(__builtin_amdgcn_sinf)
    return __builtin_amdgcn_sinf(x);
#else
    return __sinf(x * 6.28318530717958647692f);
#endif
}
__device__ __forceinline__ float fcos_rev(float x) {
#if __has_builtin(__builtin_amdgcn_cosf)
    return __builtin_amdgcn_cosf(x);
#else
    return __cosf(x * 6.28318530717958647692f);
#endif
}

// attn LDS swizzle: slot = chunk ^ SWZ(row); 2-way (free) bank aliasing
#define SWZ(row) (((row) & 7) ^ (((row) >> 3) & 1))

// ---------------------------------------------------------------------------
// K0: FUSED prep: rmsnorm (blocks 0..4095) + weight transposes + RoPE table
// ---------------------------------------------------------------------------
__global__ __launch_bounds__(256) void prep_kernel(
    const float* __restrict__ x, const float* __restrict__ gamma,
    const float* __restrict__ w_qkv, const float* __restrict__ w_out,
    const float* __restrict__ w_mix, const float* __restrict__ w_gates,
    unsigned short* __restrict__ xnb,
    unsigned short* __restrict__ wqkvT, unsigned short* __restrict__ woutT,
    unsigned short* __restrict__ wmgT, float* __restrict__ rtab)
{
    __shared__ float t[32][33];
    __shared__ float wred[4];
    const int bid = blockIdx.x;
    const int tid = threadIdx.x;

    if (bid < ROWS) {
        const int row = bid;
        const float4 xv = ((const float4*)(x + (size_t)row * DIMSZ))[tid];
        float ss = xv.x*xv.x + xv.y*xv.y + xv.z*xv.z + xv.w*xv.w;
        #pragma unroll
        for (int off = 1; off < 64; off <<= 1) ss += __shfl_xor(ss, off);
        if ((tid & 63) == 0) wred[tid >> 6] = ss;
        __syncthreads();
        const float total = wred[0] + wred[1] + wred[2] + wred[3];
        const float inv = 32.0f / fmaxf(sqrtf(total), 1e-12f);
        const float4 gv = ((const float4*)gamma)[tid];
        uint2 pk;
        pk.x = pack_bf16(xv.x * inv * gv.x, xv.y * inv * gv.y);
        pk.y = pack_bf16(xv.z * inv * gv.z, xv.w * inv * gv.w);
        ((uint2*)(xnb + (size_t)row * DIMSZ))[tid] = pk;
        return;
    }

    const int tb = bid - ROWS;           // [0, 4160)
    const int bx = tb % 130;
    const int k0 = (tb / 130) * 32;
    const int tx = tid & 31, tyy = tid >> 5;
    if (bx < 128) {
        const float* src;
        unsigned short* dst;
        int N, n0;
        if (bx < 96) { src = w_qkv; dst = wqkvT; N = 3*DIMSZ; n0 = bx*32; }
        else         { src = w_out; dst = woutT; N = DIMSZ;   n0 = (bx-96)*32; }
        #pragma unroll
        for (int i = 0; i < 4; i++)
            t[tyy*4 + i][tx] = src[(size_t)(k0 + tyy*4 + i)*N + n0 + tx];
        __syncthreads();
        #pragma unroll
        for (int i = 0; i < 4; i++)
            dst[(size_t)(n0 + tyy*4 + i)*DIMSZ + k0 + tx] = bf16r(t[tx][tyy*4 + i]);
    } else if (bx == 128) {
        #pragma unroll
        for (int i = 0; i < 4; i++) {
            const int kk = k0 + tyy*4 + i;
            t[tyy*4 + i][tx] = (tx < 16) ? w_mix[kk*16 + tx]
                                         : w_gates[kk*16 + (tx - 16)];
        }
        __syncthreads();
        #pragma unroll
        for (int i = 0; i < 4; i++)
            wmgT[(size_t)(tyy*4 + i)*DIMSZ + k0 + tx] = bf16r(t[tx][tyy*4 + i]);
    } else {
        const int pos = (k0 >> 5)*64 + (tid >> 2);
        const int f0 = (tid & 3) * 8;
        float2* dst = (float2*)rtab + (size_t)pos*32 + f0;
        #pragma unroll
        for (int tt = 0; tt < 8; tt++) {
            const float pf = (float)(f0 + tt);
            const float rev = (float)pos * fexp2(-pf * 0.41524101186092029f
                                                 - 2.6514961294723187f);
            const float rf = rev - floorf(rev);
            float2 cs;
            cs.x = fcos_rev(rf);
            cs.y = fsin_rev(rf);
            dst[tt] = cs;
        }
    }
}

// ---------------------------------------------------------------------------
// K2: FUSED gemm_qkv + mix_gates in ONE launch (they are independent, both
// depending only on prep outputs; mix's 128-block grid previously ran alone
// on a half-idle machine between prep and qkv). Blocks 0..767: qkv GEMM
// (3-ring, counted vmcnt(4), f32-wbuf epilogue -- round-10 verified).
// Blocks 768..895: mix/gates (BM=32, 4-wave K-split -- round-9 verified).
// Shared-memory pool aliased between the two paths (48KB each).
// ---------------------------------------------------------------------------
__device__ __forceinline__ void stage_qkv(
    const unsigned short* A, const unsigned short* BT,
    short* as, short* bs, int bm, int bn, int kk, int tid)
{
    #pragma unroll
    for (int r = 0; r < 2; r++) {
        const int ch = tid + 256*r;
        const int row = ch >> 2, j = ch & 3;
        gl2lds16(A  + (size_t)(bm + row)*DIMSZ + kk + j*8, (void*)(as + ch*8));
        gl2lds16(BT + (size_t)(bn + row)*DIMSZ + kk + j*8, (void*)(bs + ch*8));
    }
}

__global__ __launch_bounds__(256) void gemm_qkv_mix_fused(
    const unsigned short* __restrict__ A, const unsigned short* __restrict__ BT,
    const unsigned short* __restrict__ WG,
    const float* __restrict__ b_mix, const float* __restrict__ b_gates,
    unsigned short* __restrict__ qb, unsigned short* __restrict__ kb,
    float* __restrict__ vb,
    float* __restrict__ mixo, float* __restrict__ gateso)
{
    __shared__ char ldsb[98304];             // 96KB pool (qkv: 96KB, mix: 48KB)
    const int tid = threadIdx.x;
    const int bid0 = blockIdx.y * gridDim.x + blockIdx.x;

    if (bid0 >= 768) {
        // ================= mix/gates path (128 blocks) =================
        short (*As)[2][32*32] = (short(*)[2][32*32])(ldsb);
        short (*Bs)[2][32*32] = (short(*)[2][32*32])(ldsb + 16384);
        float (*red)[32*32]   = (float(*)[32*32])(ldsb + 32768);
        const int wv = tid >> 6, lane = tid & 63;
        const int g = lane >> 4, c = lane & 15;
        const int bm = (bid0 - 768) * 32;
        const int kbase = wv * 256;

        floatx4 acc[2][2];
        #pragma unroll
        for (int mt = 0; mt < 2; mt++)
            #pragma unroll
            for (int nt = 0; nt < 2; nt++) acc[mt][nt] = (floatx4){0.f,0.f,0.f,0.f};

        #pragma unroll
        for (int r = 0; r < 2; r++) {
            const int ch = lane + 64*r;
            const int row = ch >> 2, cc = ch & 3;
            gl2lds16(A  + (size_t)(bm + row)*DIMSZ + kbase + cc*8, (void*)(&As[wv][0][0] + ch*8));
            gl2lds16(WG + (size_t)row*DIMSZ        + kbase + cc*8, (void*)(&Bs[wv][0][0] + ch*8));
        }
        for (int i = 0; i < 8; i++) {
            const int cur = i & 1;
            if (i < 7) {
                const int k0 = kbase + (i + 1)*32;
                #pragma unroll
                for (int r = 0; r < 2; r++) {
                    const int ch = lane + 64*r;
                    const int row = ch >> 2, cc = ch & 3;
                    gl2lds16(A  + (size_t)(bm + row)*DIMSZ + k0 + cc*8, (void*)(&As[wv][cur^1][0] + ch*8));
                    gl2lds16(WG + (size_t)row*DIMSZ        + k0 + cc*8, (void*)(&Bs[wv][cur^1][0] + ch*8));
                }
                asm volatile("s_waitcnt vmcnt(4)" ::: "memory");
            } else {
                asm volatile("s_waitcnt vmcnt(0)" ::: "memory");
            }
            __builtin_amdgcn_sched_barrier(0);
            short8 af[2], bf[2];
            #pragma unroll
            for (int mt = 0; mt < 2; mt++) af[mt] = *(const short8*)(&As[wv][cur][0] + (mt*16 + c)*32 + g*8);
            #pragma unroll
            for (int nt = 0; nt < 2; nt++) bf[nt] = *(const short8*)(&Bs[wv][cur][0] + (nt*16 + c)*32 + g*8);
            #pragma unroll
            for (int mt = 0; mt < 2; mt++)
                #pragma unroll
                for (int nt = 0; nt < 2; nt++)
                    acc[mt][nt] = MFMA16(af[mt], bf[nt], acc[mt][nt]);
        }
        #pragma unroll
        for (int mt = 0; mt < 2; mt++)
            #pragma unroll
            for (int nt = 0; nt < 2; nt++)
                #pragma unroll
                for (int r2 = 0; r2 < 4; r2++)
                    red[wv][(mt*16 + g*4 + r2)*32 + nt*16 + c] = acc[mt][nt][r2];
        __syncthreads();
        #pragma unroll
        for (int jj = 0; jj < 4; jj++) {
            const int idx = tid + jj*256;
            const int row = idx >> 5, col = idx & 31;
            const float sm = (red[0][idx] + red[1][idx]) + (red[2][idx] + red[3][idx]);
            if (col < 16) {
                const float lm = sm + b_mix[col];
                mixo[(size_t)(bm + row)*HEADS + col] = 1.0f / (1.0f + fexp2(-lm * LOG2E));
            } else {
                const float lg = sm + b_gates[col - 16];
                gateso[(size_t)(bm + row)*HEADS + (col - 16)] = 1.0f / (1.0f + fexp2(-lg * LOG2E));
            }
        }
        return;
    }

    // ================= qkv GEMM path (768 blocks) =================
    short (*As)[128*32] = (short(*)[128*32])(ldsb);
    short (*Bs)[128*32] = (short(*)[128*32])(ldsb + 49152);
    const int wv = tid >> 6, lane = tid & 63;
    const int g = lane >> 4, c = lane & 15;
    const int wm = wv >> 1, wn = wv & 1;

    const int xcd = bid0 & 7, j = bid0 >> 3;           // j in [0,96)
    const int bnb = (xcd & 1)*12 + (j % 12);
    const int byb = (xcd >> 1)*8 + (j / 12);
    const int bm = byb * 128, bn = bnb * 128;

    floatx4 acc[4][4];
    #pragma unroll
    for (int mt = 0; mt < 4; mt++)
        #pragma unroll
        for (int nt = 0; nt < 4; nt++) acc[mt][nt] = (floatx4){0.f,0.f,0.f,0.f};

    stage_qkv(A, BT, &As[0][0], &Bs[0][0], bm, bn, 0,  tid);
    stage_qkv(A, BT, &As[1][0], &Bs[1][0], bm, bn, 32, tid);
    asm volatile("s_waitcnt vmcnt(4)" ::: "memory");
    __builtin_amdgcn_s_barrier();
    __builtin_amdgcn_sched_barrier(0);

    int cur = 0, nxt = 2;
    for (int i = 0; i < 32; i++) {
        const int k0 = i*32;
        if (i < 30)
            stage_qkv(A, BT, &As[nxt][0], &Bs[nxt][0], bm, bn, k0 + 64, tid);

        short8 af[4], bf[4];
        #pragma unroll
        for (int mt = 0; mt < 4; mt++) af[mt] = *(const short8*)(&As[cur][0] + (wm*64 + mt*16 + c)*32 + g*8);
        #pragma unroll
        for (int nt = 0; nt < 4; nt++) bf[nt] = *(const short8*)(&Bs[cur][0] + (wn*64 + nt*16 + c)*32 + g*8);
        __builtin_amdgcn_s_setprio(1);
        #pragma unroll
        for (int mt = 0; mt < 4; mt++)
            #pragma unroll
            for (int nt = 0; nt < 4; nt++)
                acc[mt][nt] = MFMA16(af[mt], bf[nt], acc[mt][nt]);
        __builtin_amdgcn_s_setprio(0);

        if (i < 31) {
            if (i < 30) asm volatile("s_waitcnt vmcnt(4)" ::: "memory");
            else        asm volatile("s_waitcnt vmcnt(0)" ::: "memory");
            __builtin_amdgcn_s_barrier();
            __builtin_amdgcn_sched_barrier(0);
        }
        cur = (cur == 2) ? 0 : cur + 1;
        nxt = (nxt == 2) ? 0 : nxt + 1;
    }
    __syncthreads();

    const int i3 = bn >> 10;
    const int nb = bn - (i3 << 10);
    if (i3 < 2) {
        unsigned short* dst = (i3 == 0) ? qb : kb;
        // f32 wbuf: 16 rows x 68 dwords per wave (4352B, conflict-free writes)
        float* wbuf = (float*)(&As[0][0]) + wv*1088;
        const int rd_row = lane >> 2, seg = lane & 3;
        #pragma unroll
        for (int mt = 0; mt < 4; mt++) {
            #pragma unroll
            for (int nt = 0; nt < 4; nt++)
                #pragma unroll
                for (int r2 = 0; r2 < 4; r2++)
                    wbuf[(g*4 + r2)*68 + nt*16 + c] = acc[mt][nt][r2];
            __builtin_amdgcn_s_waitcnt(0xc07f);
            const float* rp = wbuf + rd_row*68 + seg*16;
            const float4 f0 = *(const float4*)(rp + 0);
            const float4 f1 = *(const float4*)(rp + 4);
            const float4 f2 = *(const float4*)(rp + 8);
            const float4 f3 = *(const float4*)(rp + 12);
            unsigned o[8];
            o[0] = cvtpk(f0.x, f0.y); o[1] = cvtpk(f0.z, f0.w);
            o[2] = cvtpk(f1.x, f1.y); o[3] = cvtpk(f1.z, f1.w);
            o[4] = cvtpk(f2.x, f2.y); o[5] = cvtpk(f2.z, f2.w);
            o[6] = cvtpk(f3.x, f3.y); o[7] = cvtpk(f3.z, f3.w);
            const int row = bm + wm*64 + mt*16 + rd_row;
            const int col = nb + wn*64 + seg*16;
            const int hh = col >> 6, dd = col & 63;
            const int bb2 = row >> 11, pos = row & 2047;
            unsigned short* dp = dst + (((size_t)(bb2*HEADS + hh)*NSEQ) + pos)*DHEAD + dd;
            *(uint4*)dp = (uint4){o[0], o[1], o[2], o[3]};
            *(uint4*)(dp + 8) = (uint4){o[4], o[5], o[6], o[7]};
            __builtin_amdgcn_s_waitcnt(0xc07f);
        }
    } else {
        #pragma unroll
        for (int mt = 0; mt < 4; mt++)
            #pragma unroll
            for (int nt = 0; nt < 4; nt++)
                #pragma unroll
                for (int r2 = 0; r2 < 4; r2++) {
                    const int row = bm + wm*64 + mt*16 + g*4 + r2;
                    const int col = nb + wn*64 + nt*16 + c;
                    const int hh = col >> 6, dd = col & 63;
                    const int bb2 = row >> 11, pos = row & 2047;
                    vb[(((size_t)(bb2*HEADS + hh)*NSEQ) + pos)*DHEAD + dd] = acc[mt][nt][r2];
                }
    }
}

// ---------------------------------------------------------------------------
// K3: RoPE(q,k) bf16 in-place (table-driven); v blend -> bf16 V^T
// ---------------------------------------------------------------------------
__global__ __launch_bounds__(256) void rope_blend_kernel2(
    unsigned short* __restrict__ q, unsigned short* __restrict__ k,
    const float* __restrict__ vorig, const float* __restrict__ vres,
    const float* __restrict__ mixb, const float* __restrict__ rtab,
    unsigned short* __restrict__ vT)
{
    __shared__ unsigned short vt[64*72];
    const int tid = threadIdx.x;
    const int bh = blockIdx.y, bb = bh >> 4, h = bh & 15;
    const int p0 = blockIdx.x * 64;
    {
        const int pr = tid >> 2, d0 = (tid & 3) * 16;
        const int pos = p0 + pr;
        const size_t base = ((size_t)bh*NSEQ + pos)*DHEAD + d0;

        float cs_sn[16];
        #pragma unroll
        for (int i = 0; i < 4; i++)
            *(float4*)(cs_sn + i*4) = *(const float4*)(rtab + (size_t)pos*64 + d0 + i*4);

        uint4 qr0 = *(uint4*)(q + base), qr1 = *(uint4*)(q + base + 8);
        uint4 kr0 = *(uint4*)(k + base), kr1 = *(uint4*)(k + base + 8);
        unsigned qw[8] = {qr0.x, qr0.y, qr0.z, qr0.w, qr1.x, qr1.y, qr1.z, qr1.w};
        unsigned kw[8] = {kr0.x, kr0.y, kr0.z, kr0.w, kr1.x, kr1.y, kr1.z, kr1.w};
        const float QSC = SCALE * LOG2E;
        #pragma unroll
        for (int j = 0; j < 8; j++) {
            const float cs = cs_sn[2*j], sn = cs_sn[2*j + 1];
            float2 qv = bf2f(qw[j]);
            float2 kv = bf2f(kw[j]);
            const float q1 = qv.x*cs - qv.y*sn, q2 = qv.x*sn + qv.y*cs;
            const float k1 = kv.x*cs - kv.y*sn, k2 = kv.x*sn + kv.y*cs;
            qw[j] = pack_bf16(q1*QSC, q2*QSC);
            kw[j] = pack_bf16(k1, k2);
        }
        *(uint4*)(q + base)     = *(uint4*)(qw + 0);
        *(uint4*)(q + base + 8) = *(uint4*)(qw + 4);
        *(uint4*)(k + base)     = *(uint4*)(kw + 0);
        *(uint4*)(k + base + 8) = *(uint4*)(kw + 4);

        float vv[16], vr[16];
        #pragma unroll
        for (int i = 0; i < 4; i++) {
            *(float4*)(vv + i*4) = *(const float4*)(vorig + base + i*4);
            *(float4*)(vr + i*4) = *(const float4*)(vres + base + i*4);
        }
        const float mx = mixb[((size_t)(bb*NSEQ + pos))*HEADS + h];
        #pragma unroll
        for (int j = 0; j < 8; j++) {
            const float b0 = vv[2*j]*(1.f-mx)   + vr[2*j]*mx;
            const float b1 = vv[2*j+1]*(1.f-mx) + vr[2*j+1]*mx;
            vt[pr*72 + d0 + 2*j]     = bf16r(b0);
            vt[pr*72 + d0 + 2*j + 1] = bf16r(b1);
        }
    }
    __syncthreads();
    {
        const int dd = tid >> 2, c0 = (tid & 3) * 16;
        unsigned o[8];
        #pragma unroll
        for (int j = 0; j < 8; j++) {
            const unsigned a  = vt[(c0 + 2*j)*72 + dd];
            const unsigned b2 = vt[(c0 + 2*j + 1)*72 + dd];
            o[j] = a | (b2 << 16);
        }
        unsigned short* dst = vT + ((size_t)bh*DHEAD + dd)*NSEQ + p0 + c0;
        *(uint4*)(dst)     = *(uint4*)(o + 0);
        *(uint4*)(dst + 8) = *(uint4*)(o + 4);
    }
}

// ---------------------------------------------------------------------------
// K4: MFMA flash attention, 2-way GRID split-K (round-10/12 verified ~46us).
// ---------------------------------------------------------------------------
__global__ __launch_bounds__(256, 4) void attn_mfma_kernel(
    const unsigned short* __restrict__ qg,   // (32,2048,64) bf16, * SCALE*LOG2E
    const unsigned short* __restrict__ kg,   // (32,2048,64) bf16
    const unsigned short* __restrict__ vT,   // (32,64,2048) bf16
    unsigned short* __restrict__ Op0,        // (4096,1024) bf16 partial s=0
    unsigned short* __restrict__ Op1,        // (4096,1024) bf16 partial s=1
    float* __restrict__ lpart)               // (2,4096,16) fp32
{
    __shared__ short Kt[2][64*64];
    __shared__ short Vt[2][64*64];

    const int tid = threadIdx.x;
    const int w = tid >> 6, lane = tid & 63;
    const int hi = lane >> 5, cq = lane & 31;

    int wg = blockIdx.y * gridDim.x + blockIdx.x;
    wg = (wg & 7) * 128 + (wg >> 3);
    const int q0 = (wg & 15) * 128;
    const int byy = wg >> 4;
    const int bh = byy >> 1, s = byy & 1;
    const int bb = bh >> 4, h = bh & 15;

    short8 qf[4];
    #pragma unroll
    for (int kd = 0; kd < 4; kd++)
        qf[kd] = *(const short8*)(qg + ((size_t)bh*NSEQ + q0 + w*32 + cq)*DHEAD + kd*16 + hi*8);

    floatx16 O0{}, O1{};
    float lsum = 0.f;

    const unsigned short* kbase = kg + (size_t)bh*NSEQ*DHEAD;
    const unsigned short* vbase = vT + (size_t)bh*DHEAD*NSEQ;

    {
        const int kt = s*16;
        #pragma unroll
        for (int r = 0; r < 2; r++) {
            const int ch = tid + 256*r;
            const int row = ch >> 3;
            const int u = (ch & 7) ^ SWZ(row);
            gl2lds16(kbase + (size_t)(kt*64 + row)*DHEAD + u*8, (void*)(&Kt[0][0] + ch*8));
            gl2lds16(vbase + (size_t)row*NSEQ + kt*64 + u*8,   (void*)(&Vt[0][0] + ch*8));
        }
    }
    __syncthreads();

    for (int i = 0; i < 16; i++) {
        const int cur = i & 1;
        const short* Ktc = &Kt[cur][0];
        const short* Vtc = &Vt[cur][0];

        if (i < 15) {
            const int kt = s*16 + i + 1;
            short* Ktn = &Kt[cur ^ 1][0];
            short* Vtn = &Vt[cur ^ 1][0];
            #pragma unroll
            for (int r = 0; r < 2; r++) {
                const int ch = tid + 256*r;
                const int row = ch >> 3;
                const int u = (ch & 7) ^ SWZ(row);
                gl2lds16(kbase + (size_t)(kt*64 + row)*DHEAD + u*8, (void*)(Ktn + ch*8));
                gl2lds16(vbase + (size_t)row*NSEQ + kt*64 + u*8,   (void*)(Vtn + ch*8));
            }
        }

        floatx16 accS0{}, accS1{};
        __builtin_amdgcn_s_setprio(1);
        #pragma unroll
        for (int kd = 0; kd < 4; kd++) {
            const int r0 = cq, r1 = 32 + cq;
            short8 kf0 = *(const short8*)(Ktc + r0*64 + (((kd*2 + hi) ^ SWZ(r0)) * 8));
            short8 kf1 = *(const short8*)(Ktc + r1*64 + (((kd*2 + hi) ^ SWZ(r1)) * 8));
            accS0 = MFMA32(kf0, qf[kd], accS0);
            accS1 = MFMA32(kf1, qf[kd], accS1);
        }
        __builtin_amdgcn_s_setprio(0);

        #pragma unroll
        for (int kt2 = 0; kt2 < 2; kt2++) {
            const floatx16 accS = kt2 ? accS1 : accS0;

            float p[16];
            #pragma unroll
            for (int r = 0; r < 16; r++) p[r] = fexp2(accS[r]);
            const float a1 = (p[0]+p[1]) + (p[2]+p[3]);
            const float a2 = (p[4]+p[5]) + (p[6]+p[7]);
            const float a3 = (p[8]+p[9]) + (p[10]+p[11]);
            const float a4 = (p[12]+p[13]) + (p[14]+p[15]);
            lsum += (a1+a2) + (a3+a4);

            unsigned d0 = cvtpk(p[0],  p[1]);
            unsigned d1 = cvtpk(p[2],  p[3]);
            unsigned d2 = cvtpk(p[4],  p[5]);
            unsigned d3 = cvtpk(p[6],  p[7]);
            unsigned d4 = cvtpk(p[8],  p[9]);
            unsigned d5 = cvtpk(p[10], p[11]);
            unsigned d6 = cvtpk(p[12], p[13]);
            unsigned d7 = cvtpk(p[14], p[15]);
            pl32swap(d0, d2);
            pl32swap(d1, d3);
            pl32swap(d4, d6);
            pl32swap(d5, d7);
            const uintx4 t0 = {d0, d1, d2, d3};
            const uintx4 t1 = {d4, d5, d6, d7};
            const short8 pf0 = __builtin_bit_cast(short8, t0);
            const short8 pf1 = __builtin_bit_cast(short8, t1);

            __builtin_amdgcn_s_setprio(1);
            #pragma unroll
            for (int ks2 = 0; ks2 < 2; ks2++) {
                const short8 pf = ks2 ? pf1 : pf0;
                #pragma unroll
                for (int nt2 = 0; nt2 < 2; nt2++) {
                    const int rv = nt2*32 + cq;
                    short8 vf = *(const short8*)(Vtc + rv*64 + (((kt2*4 + ks2*2 + hi) ^ SWZ(rv)) * 8));
                    if (nt2 == 0) O0 = MFMA32(pf, vf, O0);
                    else          O1 = MFMA32(pf, vf, O1);
                }
            }
            __builtin_amdgcn_s_setprio(0);
        }
        __syncthreads();
    }

    unsigned short* Op = s ? Op1 : Op0;
    float l = lsum + __shfl_xor(lsum, 32);
    if (hi == 0)
        lpart[((size_t)s*ROWS + bb*NSEQ + q0 + w*32 + cq)*HEADS + h] = l;
    #pragma unroll
    for (int reg = 0; reg < 16; reg++) {
        const int qq = (reg & 3) + 8*(reg >> 2) + 4*hi;
        const int rowg = q0 + w*32 + qq;
        unsigned short* op = Op + ((size_t)(bb*NSEQ + rowg))*DIMSZ + h*DHEAD + cq;
        op[0]  = bf16r(O0[reg]);
        op[32] = bf16r(O1[reg]);
    }
}

// ---------------------------------------------------------------------------
// K5: bf16 MFMA GEMM with FUSED split-K combine (round-12 verified).
// ---------------------------------------------------------------------------
__global__ __launch_bounds__(256) void gemm_out_fused(
    const unsigned short* __restrict__ Op0, const unsigned short* __restrict__ Op1,
    const float* __restrict__ lpart, const float* __restrict__ gates,
    const unsigned short* __restrict__ BT, float* __restrict__ out0)
{
    __shared__ short As[2][64*32];
    __shared__ short Bs[2][64*32];
    __shared__ float scs[64*16];
    const int tid = threadIdx.x;
    const int wv = tid >> 6, lane = tid & 63;
    const int g = lane >> 4, c = lane & 15;
    const int wm = wv >> 1, wn = wv & 1;

    const int id = blockIdx.y * gridDim.x + blockIdx.x;
    const int xcd = id & 7, j = id >> 3;               // j in [0,128)
    const int bnb = j & 15, byb = xcd*8 + (j >> 4);
    const int bm = byb * 64, bn = bnb * 64;

    const int arow = tid >> 2, aseg = tid & 3;   // A staging: 8 bf16/thread

    uint4 a0 = *(const uint4*)(Op0 + (size_t)(bm + arow)*DIMSZ + aseg*8);
    uint4 a1 = *(const uint4*)(Op1 + (size_t)(bm + arow)*DIMSZ + aseg*8);
    gl2lds16(BT + (size_t)(bn + arow)*DIMSZ + aseg*8, (void*)(&Bs[0][0] + tid*8));

    #pragma unroll
    for (int e = 0; e < 4; e++) {
        const int n = tid + e*256;
        const int r = n >> 4, h = n & 15;
        const int row = bm + r;
        const float l0 = lpart[(size_t)row*HEADS + h];
        const float l1 = lpart[((size_t)ROWS + row)*HEADS + h];
        scs[n] = gates[(size_t)row*HEADS + h] / (l0 + l1);
    }
    __syncthreads();
    {
        const float sc = scs[arow*16 + 0];
        const unsigned aw[4] = {a0.x, a0.y, a0.z, a0.w};
        const unsigned bw[4] = {a1.x, a1.y, a1.z, a1.w};
        unsigned o[4];
        #pragma unroll
        for (int jj = 0; jj < 4; jj++) {
            const float2 fa = bf2f(aw[jj]);
            const float2 fb = bf2f(bw[jj]);
            o[jj] = cvtpk((fa.x + fb.x)*sc, (fa.y + fb.y)*sc);
        }
        *(uint4*)(&As[0][0] + arow*32 + aseg*8) = (uint4){o[0], o[1], o[2], o[3]};
    }
    __syncthreads();

    floatx4 acc[2][2];
    #pragma unroll
    for (int mt = 0; mt < 2; mt++)
        #pragma unroll
        for (int nt = 0; nt < 2; nt++) acc[mt][nt] = (floatx4){0.f,0.f,0.f,0.f};

    for (int i = 0; i < 32; i++) {
        const int cur = i & 1;
        if (i < 31) {
            const int k0 = (i + 1)*32;
            a0 = *(const uint4*)(Op0 + (size_t)(bm + arow)*DIMSZ + k0 + aseg*8);
            a1 = *(const uint4*)(Op1 + (size_t)(bm + arow)*DIMSZ + k0 + aseg*8);
            gl2lds16(BT + (size_t)(bn + arow)*DIMSZ + k0 + aseg*8, (void*)(&Bs[cur^1][0] + tid*8));
        }

        short8 af[2], bf[2];
        #pragma unroll
        for (int mt = 0; mt < 2; mt++) af[mt] = *(const short8*)(&As[cur][0] + (wm*32 + mt*16 + c)*32 + g*8);
        #pragma unroll
        for (int nt = 0; nt < 2; nt++) bf[nt] = *(const short8*)(&Bs[cur][0] + (wn*32 + nt*16 + c)*32 + g*8);
        __builtin_amdgcn_s_setprio(1);
        #pragma unroll
        for (int mt = 0; mt < 2; mt++)
            #pragma unroll
            for (int nt = 0; nt < 2; nt++)
                acc[mt][nt] = MFMA16(af[mt], bf[nt], acc[mt][nt]);
        __builtin_amdgcn_s_setprio(0);

        if (i < 31) {
            const float sc = scs[arow*16 + ((i + 1) >> 1)];
            const unsigned aw[4] = {a0.x, a0.y, a0.z, a0.w};
            const unsigned bw[4] = {a1.x, a1.y, a1.z, a1.w};
            unsigned o[4];
            #pragma unroll
            for (int jj = 0; jj < 4; jj++) {
                const float2 fa = bf2f(aw[jj]);
                const float2 fb = bf2f(bw[jj]);
                o[jj] = cvtpk((fa.x + fb.x)*sc, (fa.y + fb.y)*sc);
            }
            *(uint4*)(&As[cur^1][0] + arow*32 + aseg*8) = (uint4){o[0], o[1], o[2], o[3]};
        }
        __syncthreads();
    }

    #pragma unroll
    for (int mt = 0; mt < 2; mt++)
        #pragma unroll
        for (int nt = 0; nt < 2; nt++)
            #pragma unroll
            for (int r2 = 0; r2 < 4; r2++) {
                const int row = bm + wm*32 + mt*16 + g*4 + r2;
                const int col = bn + wn*32 + nt*16 + c;
                out0[(size_t)row*DIMSZ + col] = acc[mt][nt][r2];
            }
}

// ---------------------------------------------------------------------------
extern "C" void kernel_launch(void* const* d_in, const int* in_sizes, int n_in,
                              void* d_out, int out_size, void* d_ws, size_t ws_size,
                              hipStream_t stream) {
    const float* x       = (const float*)d_in[0];
    const float* vres    = (const float*)d_in[1];
    const float* gamma   = (const float*)d_in[2];
    const float* w_qkv   = (const float*)d_in[3];
    const float* w_mix   = (const float*)d_in[4];
    const float* b_mix   = (const float*)d_in[5];
    const float* w_gates = (const float*)d_in[6];
    const float* b_gates = (const float*)d_in[7];
    const float* w_out   = (const float*)d_in[8];

    float* out0 = (float*)d_out;                 // (2,2048,1024)
    float* out1 = out0 + (size_t)ROWS * DIMSZ;   // (2,16,2048,64) = original v

    char* ws = (char*)d_ws;
    unsigned short* xnb   = (unsigned short*)(ws);                    // 8 MB
    unsigned short* wqkvT = (unsigned short*)(ws + (8u<<20));         // 6 MB
    unsigned short* woutT = (unsigned short*)(ws + (14u<<20));        // 2 MB
    unsigned short* qb2   = (unsigned short*)(ws + (16u<<20));        // 8 MB
    unsigned short* kb2   = (unsigned short*)(ws + (24u<<20));        // 8 MB
    unsigned short* vT    = (unsigned short*)(ws + (32u<<20));        // 8 MB
    unsigned short* Op0   = (unsigned short*)(ws + (40u<<20));        // 8 MB
    float*          mixb  = (float*)(ws + (48u<<20));                 // 256 KB
    float*          gatesb= (float*)(ws + (48u<<20) + 262144);        // 256 KB
    unsigned short* wmgT  = (unsigned short*)(ws + (49u<<20));        // 64 KB
    unsigned short* Op1   = (unsigned short*)(ws + (50u<<20));        // 8 MB
    float*          lpart = (float*)(ws + (58u<<20));                 // 512 KB
    float*          rtab  = (float*)(ws + (59u<<20));                 // 512 KB

    prep_kernel<<<ROWS + 130*(DIMSZ/32), 256, 0, stream>>>(
        x, gamma, w_qkv, w_out, w_mix, w_gates, xnb, wqkvT, woutT, wmgT, rtab);

    gemm_qkv_mix_fused<<<896, 256, 0, stream>>>(
        xnb, wqkvT, wmgT, b_mix, b_gates, qb2, kb2, out1, mixb, gatesb);

    rope_blend_kernel2<<<dim3(NSEQ/64, BATCH*HEADS), 256, 0, stream>>>(
        qb2, kb2, out1, vres, mixb, rtab, vT);

    attn_mfma_kernel<<<dim3(NSEQ/128, BATCH*HEADS*2), 256, 0, stream>>>(
        qb2, kb2, vT, Op0, Op1, lpart);

    gemm_out_fused<<<dim3(DIMSZ/64, ROWS/64), 256, 0, stream>>>(
        Op0, Op1, lpart, gatesb, woutT, out0);
}

// Round 14
// 220.681 us; speedup vs baseline: 1.0741x; 1.0741x over previous
//
#include <hip/hip_runtime.h>
#include <hip/hip_bf16.h>
#include <math.h>

#define DIMSZ 1024
#define HEADS 16
#define DHEAD 64
#define NSEQ  2048
#define BATCH 2
#define ROWS  (BATCH*NSEQ)        // 4096
#define SCALE 0.125f
#define LOG2E 1.4426950408889634f

typedef __attribute__((ext_vector_type(8))) short short8;
typedef __attribute__((ext_vector_type(4))) float floatx4;
typedef __attribute__((ext_vector_type(16))) float floatx16;
typedef __attribute__((ext_vector_type(4))) unsigned uintx4;

#define MFMA16(a,b,c) __builtin_amdgcn_mfma_f32_16x16x32_bf16(a,b,c,0,0,0)
#define MFMA32(a,b,c) __builtin_amdgcn_mfma_f32_32x32x16_bf16(a,b,c,0,0,0)

__device__ __forceinline__ void gl2lds16(const void* g, void* l) {
    __builtin_amdgcn_global_load_lds(
        (const __attribute__((address_space(1))) unsigned int*)g,
        (__attribute__((address_space(3))) unsigned int*)l, 16, 0, 0);
}

// branch-free RNE f32->bf16 (finite values only)
__device__ __forceinline__ unsigned short bf16r(float a) {
    unsigned u = __float_as_uint(a);
    u += 0x7fff + ((u >> 16) & 1);
    return (unsigned short)(u >> 16);
}
__device__ __forceinline__ unsigned pack_bf16(float a, float b) {
    unsigned ua = __float_as_uint(a), ub = __float_as_uint(b);
    ua += 0x7fff + ((ua >> 16) & 1);
    ub += 0x7fff + ((ub >> 16) & 1);
    return (ua >> 16) | (ub & 0xffff0000u);
}
__device__ __forceinline__ float2 bf2f(unsigned u) {
    float2 r;
    r.x = __uint_as_float(u << 16);
    r.y = __uint_as_float(u & 0xffff0000u);
    return r;
}
// RNE f32 pair -> packed bf16 dword in ONE VALU op
__device__ __forceinline__ unsigned cvtpk(float lo, float hi) {
    unsigned r;
    asm("v_cvt_pk_bf16_f32 %0, %1, %2" : "=v"(r) : "v"(lo), "v"(hi));
    return r;
}
// swap upper 32 lanes of a with lower 32 lanes of b
__device__ __forceinline__ void pl32swap(unsigned &a, unsigned &b) {
#if __has_builtin(__builtin_amdgcn_permlane32_swap)
    auto r = __builtin_amdgcn_permlane32_swap(a, b, false, false);
    a = (unsigned)r[0]; b = (unsigned)r[1];
#else
    asm volatile("v_permlane32_swap_b32 %0, %1" : "+v"(a), "+v"(b));
#endif
}
__device__ __forceinline__ float fexp2(float x) {
#if __has_builtin(__builtin_amdgcn_exp2f)
    return __builtin_amdgcn_exp2f(x);
#else
    return exp2f(x);
#endif
}
__device__ __forceinline__ float fsin_rev(float x) {
#if __has_builtin(__builtin_amdgcn_sinf)
    return __builtin_amdgcn_sinf(x);
#else
    return __sinf(x * 6.28318530717958647692f);
#endif
}
__device__ __forceinline__ float fcos_rev(float x) {
#if __has_builtin(__builtin_amdgcn_cosf)
    return __builtin_amdgcn_cosf(x);
#else
    return __cosf(x * 6.28318530717958647692f);
#endif
}

// attn LDS swizzle: slot = chunk ^ SWZ(row); 2-way (free) bank aliasing
#define SWZ(row) (((row) & 7) ^ (((row) >> 3) & 1))

// ---------------------------------------------------------------------------
// K0: FUSED prep: rmsnorm (blocks 0..4095) + weight transposes + RoPE table
// ---------------------------------------------------------------------------
__global__ __launch_bounds__(256) void prep_kernel(
    const float* __restrict__ x, const float* __restrict__ gamma,
    const float* __restrict__ w_qkv, const float* __restrict__ w_out,
    const float* __restrict__ w_mix, const float* __restrict__ w_gates,
    unsigned short* __restrict__ xnb,
    unsigned short* __restrict__ wqkvT, unsigned short* __restrict__ woutT,
    unsigned short* __restrict__ wmgT, float* __restrict__ rtab)
{
    __shared__ float t[32][33];
    __shared__ float wred[4];
    const int bid = blockIdx.x;
    const int tid = threadIdx.x;

    if (bid < ROWS) {
        const int row = bid;
        const float4 xv = ((const float4*)(x + (size_t)row * DIMSZ))[tid];
        float ss = xv.x*xv.x + xv.y*xv.y + xv.z*xv.z + xv.w*xv.w;
        #pragma unroll
        for (int off = 1; off < 64; off <<= 1) ss += __shfl_xor(ss, off);
        if ((tid & 63) == 0) wred[tid >> 6] = ss;
        __syncthreads();
        const float total = wred[0] + wred[1] + wred[2] + wred[3];
        const float inv = 32.0f / fmaxf(sqrtf(total), 1e-12f);
        const float4 gv = ((const float4*)gamma)[tid];
        uint2 pk;
        pk.x = pack_bf16(xv.x * inv * gv.x, xv.y * inv * gv.y);
        pk.y = pack_bf16(xv.z * inv * gv.z, xv.w * inv * gv.w);
        ((uint2*)(xnb + (size_t)row * DIMSZ))[tid] = pk;
        return;
    }

    const int tb = bid - ROWS;           // [0, 4160)
    const int bx = tb % 130;
    const int k0 = (tb / 130) * 32;
    const int tx = tid & 31, tyy = tid >> 5;
    if (bx < 128) {
        const float* src;
        unsigned short* dst;
        int N, n0;
        if (bx < 96) { src = w_qkv; dst = wqkvT; N = 3*DIMSZ; n0 = bx*32; }
        else         { src = w_out; dst = woutT; N = DIMSZ;   n0 = (bx-96)*32; }
        #pragma unroll
        for (int i = 0; i < 4; i++)
            t[tyy*4 + i][tx] = src[(size_t)(k0 + tyy*4 + i)*N + n0 + tx];
        __syncthreads();
        #pragma unroll
        for (int i = 0; i < 4; i++)
            dst[(size_t)(n0 + tyy*4 + i)*DIMSZ + k0 + tx] = bf16r(t[tx][tyy*4 + i]);
    } else if (bx == 128) {
        #pragma unroll
        for (int i = 0; i < 4; i++) {
            const int kk = k0 + tyy*4 + i;
            t[tyy*4 + i][tx] = (tx < 16) ? w_mix[kk*16 + tx]
                                         : w_gates[kk*16 + (tx - 16)];
        }
        __syncthreads();
        #pragma unroll
        for (int i = 0; i < 4; i++)
            wmgT[(size_t)(tyy*4 + i)*DIMSZ + k0 + tx] = bf16r(t[tx][tyy*4 + i]);
    } else {
        const int pos = (k0 >> 5)*64 + (tid >> 2);
        const int f0 = (tid & 3) * 8;
        float2* dst = (float2*)rtab + (size_t)pos*32 + f0;
        #pragma unroll
        for (int tt = 0; tt < 8; tt++) {
            const float pf = (float)(f0 + tt);
            const float rev = (float)pos * fexp2(-pf * 0.41524101186092029f
                                                 - 2.6514961294723187f);
            const float rf = rev - floorf(rev);
            float2 cs;
            cs.x = fcos_rev(rf);
            cs.y = fsin_rev(rf);
            dst[tt] = cs;
        }
    }
}

// ---------------------------------------------------------------------------
// K2: FUSED gemm_qkv + mix_gates in ONE launch. Round-13 ERRATUM fixed:
// LDS pool is 48KB (qkv 3-ring As 24K + Bs 24K -- matches the standalone
// kernel's LDS_Block_Size=49152), NOT 96KB (round-13's mis-sized pool gave
// 1 block/CU, occupancy 9.7%, +15us). mix path: As 16K | Bs 16K | red 16K.
// Blocks 0..767: qkv GEMM. Blocks 768..895: mix/gates.
// ---------------------------------------------------------------------------
__device__ __forceinline__ void stage_qkv(
    const unsigned short* A, const unsigned short* BT,
    short* as, short* bs, int bm, int bn, int kk, int tid)
{
    #pragma unroll
    for (int r = 0; r < 2; r++) {
        const int ch = tid + 256*r;
        const int row = ch >> 2, j = ch & 3;
        gl2lds16(A  + (size_t)(bm + row)*DIMSZ + kk + j*8, (void*)(as + ch*8));
        gl2lds16(BT + (size_t)(bn + row)*DIMSZ + kk + j*8, (void*)(bs + ch*8));
    }
}

__global__ __launch_bounds__(256) void gemm_qkv_mix_fused(
    const unsigned short* __restrict__ A, const unsigned short* __restrict__ BT,
    const unsigned short* __restrict__ WG,
    const float* __restrict__ b_mix, const float* __restrict__ b_gates,
    unsigned short* __restrict__ qb, unsigned short* __restrict__ kb,
    float* __restrict__ vb,
    float* __restrict__ mixo, float* __restrict__ gateso)
{
    __shared__ char ldsb[49152];             // 48KB pool (both paths fit)
    const int tid = threadIdx.x;
    const int bid0 = blockIdx.y * gridDim.x + blockIdx.x;

    if (bid0 >= 768) {
        // ================= mix/gates path (128 blocks) =================
        short (*As)[2][32*32] = (short(*)[2][32*32])(ldsb);            // 16K
        short (*Bs)[2][32*32] = (short(*)[2][32*32])(ldsb + 16384);    // 16K
        float (*red)[32*32]   = (float(*)[32*32])(ldsb + 32768);      // 16K
        const int wv = tid >> 6, lane = tid & 63;
        const int g = lane >> 4, c = lane & 15;
        const int bm = (bid0 - 768) * 32;
        const int kbase = wv * 256;

        floatx4 acc[2][2];
        #pragma unroll
        for (int mt = 0; mt < 2; mt++)
            #pragma unroll
            for (int nt = 0; nt < 2; nt++) acc[mt][nt] = (floatx4){0.f,0.f,0.f,0.f};

        #pragma unroll
        for (int r = 0; r < 2; r++) {
            const int ch = lane + 64*r;
            const int row = ch >> 2, cc = ch & 3;
            gl2lds16(A  + (size_t)(bm + row)*DIMSZ + kbase + cc*8, (void*)(&As[wv][0][0] + ch*8));
            gl2lds16(WG + (size_t)row*DIMSZ        + kbase + cc*8, (void*)(&Bs[wv][0][0] + ch*8));
        }
        for (int i = 0; i < 8; i++) {
            const int cur = i & 1;
            if (i < 7) {
                const int k0 = kbase + (i + 1)*32;
                #pragma unroll
                for (int r = 0; r < 2; r++) {
                    const int ch = lane + 64*r;
                    const int row = ch >> 2, cc = ch & 3;
                    gl2lds16(A  + (size_t)(bm + row)*DIMSZ + k0 + cc*8, (void*)(&As[wv][cur^1][0] + ch*8));
                    gl2lds16(WG + (size_t)row*DIMSZ        + k0 + cc*8, (void*)(&Bs[wv][cur^1][0] + ch*8));
                }
                asm volatile("s_waitcnt vmcnt(4)" ::: "memory");
            } else {
                asm volatile("s_waitcnt vmcnt(0)" ::: "memory");
            }
            __builtin_amdgcn_sched_barrier(0);
            short8 af[2], bf[2];
            #pragma unroll
            for (int mt = 0; mt < 2; mt++) af[mt] = *(const short8*)(&As[wv][cur][0] + (mt*16 + c)*32 + g*8);
            #pragma unroll
            for (int nt = 0; nt < 2; nt++) bf[nt] = *(const short8*)(&Bs[wv][cur][0] + (nt*16 + c)*32 + g*8);
            #pragma unroll
            for (int mt = 0; mt < 2; mt++)
                #pragma unroll
                for (int nt = 0; nt < 2; nt++)
                    acc[mt][nt] = MFMA16(af[mt], bf[nt], acc[mt][nt]);
        }
        #pragma unroll
        for (int mt = 0; mt < 2; mt++)
            #pragma unroll
            for (int nt = 0; nt < 2; nt++)
                #pragma unroll
                for (int r2 = 0; r2 < 4; r2++)
                    red[wv][(mt*16 + g*4 + r2)*32 + nt*16 + c] = acc[mt][nt][r2];
        __syncthreads();
        #pragma unroll
        for (int jj = 0; jj < 4; jj++) {
            const int idx = tid + jj*256;
            const int row = idx >> 5, col = idx & 31;
            const float sm = (red[0][idx] + red[1][idx]) + (red[2][idx] + red[3][idx]);
            if (col < 16) {
                const float lm = sm + b_mix[col];
                mixo[(size_t)(bm + row)*HEADS + col] = 1.0f / (1.0f + fexp2(-lm * LOG2E));
            } else {
                const float lg = sm + b_gates[col - 16];
                gateso[(size_t)(bm + row)*HEADS + (col - 16)] = 1.0f / (1.0f + fexp2(-lg * LOG2E));
            }
        }
        return;
    }

    // ================= qkv GEMM path (768 blocks) =================
    short (*As)[128*32] = (short(*)[128*32])(ldsb);            // 3 x 8K = 24K
    short (*Bs)[128*32] = (short(*)[128*32])(ldsb + 24576);    // 3 x 8K = 24K
    const int wv = tid >> 6, lane = tid & 63;
    const int g = lane >> 4, c = lane & 15;
    const int wm = wv >> 1, wn = wv & 1;

    const int xcd = bid0 & 7, j = bid0 >> 3;           // j in [0,96)
    const int bnb = (xcd & 1)*12 + (j % 12);
    const int byb = (xcd >> 1)*8 + (j / 12);
    const int bm = byb * 128, bn = bnb * 128;

    floatx4 acc[4][4];
    #pragma unroll
    for (int mt = 0; mt < 4; mt++)
        #pragma unroll
        for (int nt = 0; nt < 4; nt++) acc[mt][nt] = (floatx4){0.f,0.f,0.f,0.f};

    stage_qkv(A, BT, &As[0][0], &Bs[0][0], bm, bn, 0,  tid);
    stage_qkv(A, BT, &As[1][0], &Bs[1][0], bm, bn, 32, tid);
    asm volatile("s_waitcnt vmcnt(4)" ::: "memory");
    __builtin_amdgcn_s_barrier();
    __builtin_amdgcn_sched_barrier(0);

    int cur = 0, nxt = 2;
    for (int i = 0; i < 32; i++) {
        const int k0 = i*32;
        if (i < 30)
            stage_qkv(A, BT, &As[nxt][0], &Bs[nxt][0], bm, bn, k0 + 64, tid);

        short8 af[4], bf[4];
        #pragma unroll
        for (int mt = 0; mt < 4; mt++) af[mt] = *(const short8*)(&As[cur][0] + (wm*64 + mt*16 + c)*32 + g*8);
        #pragma unroll
        for (int nt = 0; nt < 4; nt++) bf[nt] = *(const short8*)(&Bs[cur][0] + (wn*64 + nt*16 + c)*32 + g*8);
        __builtin_amdgcn_s_setprio(1);
        #pragma unroll
        for (int mt = 0; mt < 4; mt++)
            #pragma unroll
            for (int nt = 0; nt < 4; nt++)
                acc[mt][nt] = MFMA16(af[mt], bf[nt], acc[mt][nt]);
        __builtin_amdgcn_s_setprio(0);

        if (i < 31) {
            if (i < 30) asm volatile("s_waitcnt vmcnt(4)" ::: "memory");
            else        asm volatile("s_waitcnt vmcnt(0)" ::: "memory");
            __builtin_amdgcn_s_barrier();
            __builtin_amdgcn_sched_barrier(0);
        }
        cur = (cur == 2) ? 0 : cur + 1;
        nxt = (nxt == 2) ? 0 : nxt + 1;
    }
    __syncthreads();

    const int i3 = bn >> 10;
    const int nb = bn - (i3 << 10);
    if (i3 < 2) {
        unsigned short* dst = (i3 == 0) ? qb : kb;
        // f32 wbuf: 16 rows x 68 dwords per wave (4352B, conflict-free writes)
        float* wbuf = (float*)(&As[0][0]) + wv*1088;
        const int rd_row = lane >> 2, seg = lane & 3;
        #pragma unroll
        for (int mt = 0; mt < 4; mt++) {
            #pragma unroll
            for (int nt = 0; nt < 4; nt++)
                #pragma unroll
                for (int r2 = 0; r2 < 4; r2++)
                    wbuf[(g*4 + r2)*68 + nt*16 + c] = acc[mt][nt][r2];
            __builtin_amdgcn_s_waitcnt(0xc07f);
            const float* rp = wbuf + rd_row*68 + seg*16;
            const float4 f0 = *(const float4*)(rp + 0);
            const float4 f1 = *(const float4*)(rp + 4);
            const float4 f2 = *(const float4*)(rp + 8);
            const float4 f3 = *(const float4*)(rp + 12);
            unsigned o[8];
            o[0] = cvtpk(f0.x, f0.y); o[1] = cvtpk(f0.z, f0.w);
            o[2] = cvtpk(f1.x, f1.y); o[3] = cvtpk(f1.z, f1.w);
            o[4] = cvtpk(f2.x, f2.y); o[5] = cvtpk(f2.z, f2.w);
            o[6] = cvtpk(f3.x, f3.y); o[7] = cvtpk(f3.z, f3.w);
            const int row = bm + wm*64 + mt*16 + rd_row;
            const int col = nb + wn*64 + seg*16;
            const int hh = col >> 6, dd = col & 63;
            const int bb2 = row >> 11, pos = row & 2047;
            unsigned short* dp = dst + (((size_t)(bb2*HEADS + hh)*NSEQ) + pos)*DHEAD + dd;
            *(uint4*)dp = (uint4){o[0], o[1], o[2], o[3]};
            *(uint4*)(dp + 8) = (uint4){o[4], o[5], o[6], o[7]};
            __builtin_amdgcn_s_waitcnt(0xc07f);
        }
    } else {
        #pragma unroll
        for (int mt = 0; mt < 4; mt++)
            #pragma unroll
            for (int nt = 0; nt < 4; nt++)
                #pragma unroll
                for (int r2 = 0; r2 < 4; r2++) {
                    const int row = bm + wm*64 + mt*16 + g*4 + r2;
                    const int col = nb + wn*64 + nt*16 + c;
                    const int hh = col >> 6, dd = col & 63;
                    const int bb2 = row >> 11, pos = row & 2047;
                    vb[(((size_t)(bb2*HEADS + hh)*NSEQ) + pos)*DHEAD + dd] = acc[mt][nt][r2];
                }
    }
}

// ---------------------------------------------------------------------------
// K3: RoPE(q,k) bf16 in-place (table-driven); v blend -> bf16 V^T
// ---------------------------------------------------------------------------
__global__ __launch_bounds__(256) void rope_blend_kernel2(
    unsigned short* __restrict__ q, unsigned short* __restrict__ k,
    const float* __restrict__ vorig, const float* __restrict__ vres,
    const float* __restrict__ mixb, const float* __restrict__ rtab,
    unsigned short* __restrict__ vT)
{
    __shared__ unsigned short vt[64*72];
    const int tid = threadIdx.x;
    const int bh = blockIdx.y, bb = bh >> 4, h = bh & 15;
    const int p0 = blockIdx.x * 64;
    {
        const int pr = tid >> 2, d0 = (tid & 3) * 16;
        const int pos = p0 + pr;
        const size_t base = ((size_t)bh*NSEQ + pos)*DHEAD + d0;

        float cs_sn[16];
        #pragma unroll
        for (int i = 0; i < 4; i++)
            *(float4*)(cs_sn + i*4) = *(const float4*)(rtab + (size_t)pos*64 + d0 + i*4);

        uint4 qr0 = *(uint4*)(q + base), qr1 = *(uint4*)(q + base + 8);
        uint4 kr0 = *(uint4*)(k + base), kr1 = *(uint4*)(k + base + 8);
        unsigned qw[8] = {qr0.x, qr0.y, qr0.z, qr0.w, qr1.x, qr1.y, qr1.z, qr1.w};
        unsigned kw[8] = {kr0.x, kr0.y, kr0.z, kr0.w, kr1.x, kr1.y, kr1.z, kr1.w};
        const float QSC = SCALE * LOG2E;
        #pragma unroll
        for (int j = 0; j < 8; j++) {
            const float cs = cs_sn[2*j], sn = cs_sn[2*j + 1];
            float2 qv = bf2f(qw[j]);
            float2 kv = bf2f(kw[j]);
            const float q1 = qv.x*cs - qv.y*sn, q2 = qv.x*sn + qv.y*cs;
            const float k1 = kv.x*cs - kv.y*sn, k2 = kv.x*sn + kv.y*cs;
            qw[j] = pack_bf16(q1*QSC, q2*QSC);
            kw[j] = pack_bf16(k1, k2);
        }
        *(uint4*)(q + base)     = *(uint4*)(qw + 0);
        *(uint4*)(q + base + 8) = *(uint4*)(qw + 4);
        *(uint4*)(k + base)     = *(uint4*)(kw + 0);
        *(uint4*)(k + base + 8) = *(uint4*)(kw + 4);

        float vv[16], vr[16];
        #pragma unroll
        for (int i = 0; i < 4; i++) {
            *(float4*)(vv + i*4) = *(const float4*)(vorig + base + i*4);
            *(float4*)(vr + i*4) = *(const float4*)(vres + base + i*4);
        }
        const float mx = mixb[((size_t)(bb*NSEQ + pos))*HEADS + h];
        #pragma unroll
        for (int j = 0; j < 8; j++) {
            const float b0 = vv[2*j]*(1.f-mx)   + vr[2*j]*mx;
            const float b1 = vv[2*j+1]*(1.f-mx) + vr[2*j+1]*mx;
            vt[pr*72 + d0 + 2*j]     = bf16r(b0);
            vt[pr*72 + d0 + 2*j + 1] = bf16r(b1);
        }
    }
    __syncthreads();
    {
        const int dd = tid >> 2, c0 = (tid & 3) * 16;
        unsigned o[8];
        #pragma unroll
        for (int j = 0; j < 8; j++) {
            const unsigned a  = vt[(c0 + 2*j)*72 + dd];
            const unsigned b2 = vt[(c0 + 2*j + 1)*72 + dd];
            o[j] = a | (b2 << 16);
        }
        unsigned short* dst = vT + ((size_t)bh*DHEAD + dd)*NSEQ + p0 + c0;
        *(uint4*)(dst)     = *(uint4*)(o + 0);
        *(uint4*)(dst + 8) = *(uint4*)(o + 4);
    }
}

// ---------------------------------------------------------------------------
// K4: MFMA flash attention, 2-way GRID split-K (round-10/12 verified ~46us).
// ---------------------------------------------------------------------------
__global__ __launch_bounds__(256, 4) void attn_mfma_kernel(
    const unsigned short* __restrict__ qg,   // (32,2048,64) bf16, * SCALE*LOG2E
    const unsigned short* __restrict__ kg,   // (32,2048,64) bf16
    const unsigned short* __restrict__ vT,   // (32,64,2048) bf16
    unsigned short* __restrict__ Op0,        // (4096,1024) bf16 partial s=0
    unsigned short* __restrict__ Op1,        // (4096,1024) bf16 partial s=1
    float* __restrict__ lpart)               // (2,4096,16) fp32
{
    __shared__ short Kt[2][64*64];
    __shared__ short Vt[2][64*64];

    const int tid = threadIdx.x;
    const int w = tid >> 6, lane = tid & 63;
    const int hi = lane >> 5, cq = lane & 31;

    int wg = blockIdx.y * gridDim.x + blockIdx.x;
    wg = (wg & 7) * 128 + (wg >> 3);
    const int q0 = (wg & 15) * 128;
    const int byy = wg >> 4;
    const int bh = byy >> 1, s = byy & 1;
    const int bb = bh >> 4, h = bh & 15;

    short8 qf[4];
    #pragma unroll
    for (int kd = 0; kd < 4; kd++)
        qf[kd] = *(const short8*)(qg + ((size_t)bh*NSEQ + q0 + w*32 + cq)*DHEAD + kd*16 + hi*8);

    floatx16 O0{}, O1{};
    float lsum = 0.f;

    const unsigned short* kbase = kg + (size_t)bh*NSEQ*DHEAD;
    const unsigned short* vbase = vT + (size_t)bh*DHEAD*NSEQ;

    {
        const int kt = s*16;
        #pragma unroll
        for (int r = 0; r < 2; r++) {
            const int ch = tid + 256*r;
            const int row = ch >> 3;
            const int u = (ch & 7) ^ SWZ(row);
            gl2lds16(kbase + (size_t)(kt*64 + row)*DHEAD + u*8, (void*)(&Kt[0][0] + ch*8));
            gl2lds16(vbase + (size_t)row*NSEQ + kt*64 + u*8,   (void*)(&Vt[0][0] + ch*8));
        }
    }
    __syncthreads();

    for (int i = 0; i < 16; i++) {
        const int cur = i & 1;
        const short* Ktc = &Kt[cur][0];
        const short* Vtc = &Vt[cur][0];

        if (i < 15) {
            const int kt = s*16 + i + 1;
            short* Ktn = &Kt[cur ^ 1][0];
            short* Vtn = &Vt[cur ^ 1][0];
            #pragma unroll
            for (int r = 0; r < 2; r++) {
                const int ch = tid + 256*r;
                const int row = ch >> 3;
                const int u = (ch & 7) ^ SWZ(row);
                gl2lds16(kbase + (size_t)(kt*64 + row)*DHEAD + u*8, (void*)(Ktn + ch*8));
                gl2lds16(vbase + (size_t)row*NSEQ + kt*64 + u*8,   (void*)(Vtn + ch*8));
            }
        }

        floatx16 accS0{}, accS1{};
        __builtin_amdgcn_s_setprio(1);
        #pragma unroll
        for (int kd = 0; kd < 4; kd++) {
            const int r0 = cq, r1 = 32 + cq;
            short8 kf0 = *(const short8*)(Ktc + r0*64 + (((kd*2 + hi) ^ SWZ(r0)) * 8));
            short8 kf1 = *(const short8*)(Ktc + r1*64 + (((kd*2 + hi) ^ SWZ(r1)) * 8));
            accS0 = MFMA32(kf0, qf[kd], accS0);
            accS1 = MFMA32(kf1, qf[kd], accS1);
        }
        __builtin_amdgcn_s_setprio(0);

        #pragma unroll
        for (int kt2 = 0; kt2 < 2; kt2++) {
            const floatx16 accS = kt2 ? accS1 : accS0;

            float p[16];
            #pragma unroll
            for (int r = 0; r < 16; r++) p[r] = fexp2(accS[r]);
            const float a1 = (p[0]+p[1]) + (p[2]+p[3]);
            const float a2 = (p[4]+p[5]) + (p[6]+p[7]);
            const float a3 = (p[8]+p[9]) + (p[10]+p[11]);
            const float a4 = (p[12]+p[13]) + (p[14]+p[15]);
            lsum += (a1+a2) + (a3+a4);

            unsigned d0 = cvtpk(p[0],  p[1]);
            unsigned d1 = cvtpk(p[2],  p[3]);
            unsigned d2 = cvtpk(p[4],  p[5]);
            unsigned d3 = cvtpk(p[6],  p[7]);
            unsigned d4 = cvtpk(p[8],  p[9]);
            unsigned d5 = cvtpk(p[10], p[11]);
            unsigned d6 = cvtpk(p[12], p[13]);
            unsigned d7 = cvtpk(p[14], p[15]);
            pl32swap(d0, d2);
            pl32swap(d1, d3);
            pl32swap(d4, d6);
            pl32swap(d5, d7);
            const uintx4 t0 = {d0, d1, d2, d3};
            const uintx4 t1 = {d4, d5, d6, d7};
            const short8 pf0 = __builtin_bit_cast(short8, t0);
            const short8 pf1 = __builtin_bit_cast(short8, t1);

            __builtin_amdgcn_s_setprio(1);
            #pragma unroll
            for (int ks2 = 0; ks2 < 2; ks2++) {
                const short8 pf = ks2 ? pf1 : pf0;
                #pragma unroll
                for (int nt2 = 0; nt2 < 2; nt2++) {
                    const int rv = nt2*32 + cq;
                    short8 vf = *(const short8*)(Vtc + rv*64 + (((kt2*4 + ks2*2 + hi) ^ SWZ(rv)) * 8));
                    if (nt2 == 0) O0 = MFMA32(pf, vf, O0);
                    else          O1 = MFMA32(pf, vf, O1);
                }
            }
            __builtin_amdgcn_s_setprio(0);
        }
        __syncthreads();
    }

    unsigned short* Op = s ? Op1 : Op0;
    float l = lsum + __shfl_xor(lsum, 32);
    if (hi == 0)
        lpart[((size_t)s*ROWS + bb*NSEQ + q0 + w*32 + cq)*HEADS + h] = l;
    #pragma unroll
    for (int reg = 0; reg < 16; reg++) {
        const int qq = (reg & 3) + 8*(reg >> 2) + 4*hi;
        const int rowg = q0 + w*32 + qq;
        unsigned short* op = Op + ((size_t)(bb*NSEQ + rowg))*DIMSZ + h*DHEAD + cq;
        op[0]  = bf16r(O0[reg]);
        op[32] = bf16r(O1[reg]);
    }
}

// ---------------------------------------------------------------------------
// K5: bf16 MFMA GEMM with FUSED split-K combine (round-12 verified).
// ---------------------------------------------------------------------------
__global__ __launch_bounds__(256) void gemm_out_fused(
    const unsigned short* __restrict__ Op0, const unsigned short* __restrict__ Op1,
    const float* __restrict__ lpart, const float* __restrict__ gates,
    const unsigned short* __restrict__ BT, float* __restrict__ out0)
{
    __shared__ short As[2][64*32];
    __shared__ short Bs[2][64*32];
    __shared__ float scs[64*16];
    const int tid = threadIdx.x;
    const int wv = tid >> 6, lane = tid & 63;
    const int g = lane >> 4, c = lane & 15;
    const int wm = wv >> 1, wn = wv & 1;

    const int id = blockIdx.y * gridDim.x + blockIdx.x;
    const int xcd = id & 7, j = id >> 3;               // j in [0,128)
    const int bnb = j & 15, byb = xcd*8 + (j >> 4);
    const int bm = byb * 64, bn = bnb * 64;

    const int arow = tid >> 2, aseg = tid & 3;   // A staging: 8 bf16/thread

    uint4 a0 = *(const uint4*)(Op0 + (size_t)(bm + arow)*DIMSZ + aseg*8);
    uint4 a1 = *(const uint4*)(Op1 + (size_t)(bm + arow)*DIMSZ + aseg*8);
    gl2lds16(BT + (size_t)(bn + arow)*DIMSZ + aseg*8, (void*)(&Bs[0][0] + tid*8));

    #pragma unroll
    for (int e = 0; e < 4; e++) {
        const int n = tid + e*256;
        const int r = n >> 4, h = n & 15;
        const int row = bm + r;
        const float l0 = lpart[(size_t)row*HEADS + h];
        const float l1 = lpart[((size_t)ROWS + row)*HEADS + h];
        scs[n] = gates[(size_t)row*HEADS + h] / (l0 + l1);
    }
    __syncthreads();
    {
        const float sc = scs[arow*16 + 0];
        const unsigned aw[4] = {a0.x, a0.y, a0.z, a0.w};
        const unsigned bw[4] = {a1.x, a1.y, a1.z, a1.w};
        unsigned o[4];
        #pragma unroll
        for (int jj = 0; jj < 4; jj++) {
            const float2 fa = bf2f(aw[jj]);
            const float2 fb = bf2f(bw[jj]);
            o[jj] = cvtpk((fa.x + fb.x)*sc, (fa.y + fb.y)*sc);
        }
        *(uint4*)(&As[0][0] + arow*32 + aseg*8) = (uint4){o[0], o[1], o[2], o[3]};
    }
    __syncthreads();

    floatx4 acc[2][2];
    #pragma unroll
    for (int mt = 0; mt < 2; mt++)
        #pragma unroll
        for (int nt = 0; nt < 2; nt++) acc[mt][nt] = (floatx4){0.f,0.f,0.f,0.f};

    for (int i = 0; i < 32; i++) {
        const int cur = i & 1;
        if (i < 31) {
            const int k0 = (i + 1)*32;
            a0 = *(const uint4*)(Op0 + (size_t)(bm + arow)*DIMSZ + k0 + aseg*8);
            a1 = *(const uint4*)(Op1 + (size_t)(bm + arow)*DIMSZ + k0 + aseg*8);
            gl2lds16(BT + (size_t)(bn + arow)*DIMSZ + k0 + aseg*8, (void*)(&Bs[cur^1][0] + tid*8));
        }

        short8 af[2], bf[2];
        #pragma unroll
        for (int mt = 0; mt < 2; mt++) af[mt] = *(const short8*)(&As[cur][0] + (wm*32 + mt*16 + c)*32 + g*8);
        #pragma unroll
        for (int nt = 0; nt < 2; nt++) bf[nt] = *(const short8*)(&Bs[cur][0] + (wn*32 + nt*16 + c)*32 + g*8);
        __builtin_amdgcn_s_setprio(1);
        #pragma unroll
        for (int mt = 0; mt < 2; mt++)
            #pragma unroll
            for (int nt = 0; nt < 2; nt++)
                acc[mt][nt] = MFMA16(af[mt], bf[nt], acc[mt][nt]);
        __builtin_amdgcn_s_setprio(0);

        if (i < 31) {
            const float sc = scs[arow*16 + ((i + 1) >> 1)];
            const unsigned aw[4] = {a0.x, a0.y, a0.z, a0.w};
            const unsigned bw[4] = {a1.x, a1.y, a1.z, a1.w};
            unsigned o[4];
            #pragma unroll
            for (int jj = 0; jj < 4; jj++) {
                const float2 fa = bf2f(aw[jj]);
                const float2 fb = bf2f(bw[jj]);
                o[jj] = cvtpk((fa.x + fb.x)*sc, (fa.y + fb.y)*sc);
            }
            *(uint4*)(&As[cur^1][0] + arow*32 + aseg*8) = (uint4){o[0], o[1], o[2], o[3]};
        }
        __syncthreads();
    }

    #pragma unroll
    for (int mt = 0; mt < 2; mt++)
        #pragma unroll
        for (int nt = 0; nt < 2; nt++)
            #pragma unroll
            for (int r2 = 0; r2 < 4; r2++) {
                const int row = bm + wm*32 + mt*16 + g*4 + r2;
                const int col = bn + wn*32 + nt*16 + c;
                out0[(size_t)row*DIMSZ + col] = acc[mt][nt][r2];
            }
}

// ---------------------------------------------------------------------------
extern "C" void kernel_launch(void* const* d_in, const int* in_sizes, int n_in,
                              void* d_out, int out_size, void* d_ws, size_t ws_size,
                              hipStream_t stream) {
    const float* x       = (const float*)d_in[0];
    const float* vres    = (const float*)d_in[1];
    const float* gamma   = (const float*)d_in[2];
    const float* w_qkv   = (const float*)d_in[3];
    const float* w_mix   = (const float*)d_in[4];
    const float* b_mix   = (const float*)d_in[5];
    const float* w_gates = (const float*)d_in[6];
    const float* b_gates = (const float*)d_in[7];
    const float* w_out   = (const float*)d_in[8];

    float* out0 = (float*)d_out;                 // (2,2048,1024)
    float* out1 = out0 + (size_t)ROWS * DIMSZ;   // (2,16,2048,64) = original v

    char* ws = (char*)d_ws;
    unsigned short* xnb   = (unsigned short*)(ws);                    // 8 MB
    unsigned short* wqkvT = (unsigned short*)(ws + (8u<<20));         // 6 MB
    unsigned short* woutT = (unsigned short*)(ws + (14u<<20));        // 2 MB
    unsigned short* qb2   = (unsigned short*)(ws + (16u<<20));        // 8 MB
    unsigned short* kb2   = (unsigned short*)(ws + (24u<<20));        // 8 MB
    unsigned short* vT    = (unsigned short*)(ws + (32u<<20));        // 8 MB
    unsigned short* Op0   = (unsigned short*)(ws + (40u<<20));        // 8 MB
    float*          mixb  = (float*)(ws + (48u<<20));                 // 256 KB
    float*          gatesb= (float*)(ws + (48u<<20) + 262144);        // 256 KB
    unsigned short* wmgT  = (unsigned short*)(ws + (49u<<20));        // 64 KB
    unsigned short* Op1   = (unsigned short*)(ws + (50u<<20));        // 8 MB
    float*          lpart = (float*)(ws + (58u<<20));                 // 512 KB
    float*          rtab  = (float*)(ws + (59u<<20));                 // 512 KB

    prep_kernel<<<ROWS + 130*(DIMSZ/32), 256, 0, stream>>>(
        x, gamma, w_qkv, w_out, w_mix, w_gates, xnb, wqkvT, woutT, wmgT, rtab);

    gemm_qkv_mix_fused<<<896, 256, 0, stream>>>(
        xnb, wqkvT, wmgT, b_mix, b_gates, qb2, kb2, out1, mixb, gatesb);

    rope_blend_kernel2<<<dim3(NSEQ/64, BATCH*HEADS), 256, 0, stream>>>(
        qb2, kb2, out1, vres, mixb, rtab, vT);

    attn_mfma_kernel<<<dim3(NSEQ/128, BATCH*HEADS*2), 256, 0, stream>>>(
        qb2, kb2, vT, Op0, Op1, lpart);

    gemm_out_fused<<<dim3(DIMSZ/64, ROWS/64), 256, 0, stream>>>(
        Op0, Op1, lpart, gatesb, woutT, out0);
}